// Round 3
// baseline (2630.838 us; speedup 1.0000x reference)
//
#include <hip/hip_runtime.h>
#include <stdint.h>

// ---------------------------------------------------------------------------
// HeteroRGCNLayer on MI355X. Inputs/outputs float32; MFMA compute in bf16.
// D=256, N_TOK=50000, N_SRL=20000, N_ENT=10000, T=50000
// E_TS=300000, E_EE=150000, E_ST=300000, E_ET=150000
// Workspace NEED = 170,620,096 bytes (fits confirmed ws >= ~170.6 MB).
// ---------------------------------------------------------------------------

typedef unsigned short u16;
typedef __bf16 bf16_t;
typedef bf16_t bf16x8 __attribute__((ext_vector_type(8)));
typedef float f32x4 __attribute__((ext_vector_type(4)));

__device__ __forceinline__ float us2f(u16 h) {
  unsigned int u = ((unsigned int)h) << 16;
  return __builtin_bit_cast(float, u);
}
__device__ __forceinline__ u16 f2us(float f) {  // RNE float->bf16
  unsigned int u = __builtin_bit_cast(unsigned int, f);
  u += 0x7FFFu + ((u >> 16) & 1u);
  return (u16)(u >> 16);
}
__device__ __forceinline__ uint4 pack8(float4 a, float4 b) {
  uint4 v;
  v.x = f2us(a.x) | ((unsigned)f2us(a.y) << 16);
  v.y = f2us(a.z) | ((unsigned)f2us(a.w) << 16);
  v.z = f2us(b.x) | ((unsigned)f2us(b.y) << 16);
  v.w = f2us(b.z) | ((unsigned)f2us(b.w) << 16);
  return v;
}
__device__ __forceinline__ float sigm(float x) { return 1.f / (1.f + __expf(-x)); }
__device__ __forceinline__ float tanh_f(float x) {
  x = fminf(fmaxf(x, -15.f), 15.f);
  float e = __expf(2.f * x);
  return (e - 1.f) / (e + 1.f);
}

// ---------------- diagnostics ---------------------------------------------
__global__ void fill_sent(float* out, int n, float v) {
  int i = blockIdx.x * 256 + threadIdx.x;
  if (i < n) out[i] = v;
}

// ---------------- CSR build ------------------------------------------------
__global__ void count_k(const int* __restrict__ dst, int E, int* __restrict__ cnt) {
  int i = blockIdx.x * 256 + threadIdx.x;
  if (i < E) atomicAdd(&cnt[dst[i]], 1);
}

__global__ __launch_bounds__(1024) void scan4_k(int* a0, int n0, int* a1, int n1,
                                                int* a2, int n2, int* a3, int n3) {
  int* a; int n;
  if (blockIdx.x == 0) { a = a0; n = n0; }
  else if (blockIdx.x == 1) { a = a1; n = n1; }
  else if (blockIdx.x == 2) { a = a2; n = n2; }
  else { a = a3; n = n3; }
  __shared__ int swv[16];
  const int t = threadIdx.x, lane = t & 63, wid = t >> 6;
  int carry = 0;
  for (int base = 0; base < n; base += 1024) {
    int r = base + t;
    int v = (r < n) ? a[r] : 0;
    int inc = v;
#pragma unroll
    for (int o = 1; o < 64; o <<= 1) {
      int x = __shfl_up(inc, o, 64);
      if (lane >= o) inc += x;
    }
    if (lane == 63) swv[wid] = inc;
    __syncthreads();
    int wbase = 0, tot = 0;
    for (int w = 0; w < 16; w++) { int s = swv[w]; tot += s; if (w < wid) wbase += s; }
    if (r < n) a[r] = carry + wbase + inc - v;  // exclusive prefix
    carry += tot;
    __syncthreads();
  }
}

__global__ void fill_k(const int* __restrict__ dst, int E, int* __restrict__ off,
                       int* __restrict__ list) {
  int i = blockIdx.x * 256 + threadIdx.x;
  if (i < E) {
    int p = atomicAdd(&off[dst[i]], 1);
    list[p] = i;
  }
}

// ---------------- prefix sums of bert emb (f32, 50001 x 256) ---------------
__global__ __launch_bounds__(256) void cumsum_P(const float* __restrict__ emb,
                                                float* __restrict__ Pm) {
  const int d = blockIdx.x, t = threadIdx.x, lane = t & 63, wid = t >> 6;
  __shared__ float sw[4];
  float carry = 0.f;
  if (t == 0) Pm[d] = 0.f;
  for (int base = 0; base < 50000; base += 256) {
    int r = base + t;
    float v = (r < 50000) ? emb[(size_t)r * 256 + d] : 0.f;
    float inc = v;
#pragma unroll
    for (int o = 1; o < 64; o <<= 1) {
      float x = __shfl_up(inc, o, 64);
      if (lane >= o) inc += x;
    }
    if (lane == 63) sw[wid] = inc;
    __syncthreads();
    float wbase = 0.f, tot = 0.f;
#pragma unroll
    for (int w = 0; w < 4; w++) { float s = sw[w]; tot += s; if (w < wid) wbase += s; }
    if (r < 50000) Pm[(size_t)(r + 1) * 256 + d] = carry + wbase + inc;
    carry += tot;
    __syncthreads();
  }
}

// ---------------- derived weights (all f32 in/out) -------------------------
// B2[r][k] = sum_j A1[r][j]*Wc[j][k]   (A1 = Watt[:, :256], Watt 256x512)
__global__ __launch_bounds__(256) void make_B2(const float* __restrict__ Watt,
                                               const float* __restrict__ Wc,
                                               float* __restrict__ B2) {
  int r = blockIdx.x, k = threadIdx.x;
  float s = 0.f;
  for (int n = 0; n < 256; n++) s += Watt[r * 512 + n] * Wc[n * 256 + k];
  B2[r * 256 + k] = s;
}
// bias2[r] = sum_k A1[r][k]*bc[k]
__global__ void make_bias2(const float* __restrict__ Watt, const float* __restrict__ bc,
                           float* __restrict__ bias2) {
  int r = threadIdx.x;
  float s = 0.f;
  for (int k = 0; k < 256; k++) s += Watt[r * 512 + k] * bc[k];
  bias2[r] = s;
}
// WW (512x256): rows 0..255 = Wc@Wr2 ; rows 256..511 = B2@Wr2
// (Wr2[n][k] = Wrel[n*512 + 256 + k], Wrel 256x512)
__global__ __launch_bounds__(256) void make_WW(const float* __restrict__ Wc,
                                               const float* __restrict__ B2,
                                               const float* __restrict__ Wrel,
                                               float* __restrict__ WW) {
  int r = blockIdx.x, k = threadIdx.x;
  const float* X = (r < 256) ? (Wc + (size_t)r * 256) : (B2 + (size_t)(r - 256) * 256);
  float s = 0.f;
  for (int n = 0; n < 256; n++) s += X[n] * Wrel[(size_t)n * 512 + 256 + k];
  WW[(size_t)r * 256 + k] = s;
}

// ---------------------------------------------------------------------------
// GEMM: C[M x *] = A[M x 256] @ B^T + bias.  bf16 MFMA 16x16x32, 64x64 tile.
// AMODE 0: A from memory (row stride 256; ASRC 0 = f32, 1 = bf16/u16).
// AMODE 2: EE chunk — A row m is edge e=lst[e_start+m]:
//          A[k] = rel[e]/(y-x) * (Pm[y][k]-Pm[x][k]); residual s2tab[src[e]].
// B is always f32 (N x 256 row-major, row stride ldb), bias f32.
// C index = m*Cstride + coff + n; OUTBF: bf16(u16) else f32.
// ---------------------------------------------------------------------------
template <int AMODE, int ASRC, bool OUTBF>
__global__ __launch_bounds__(256) void gemm_k256(
    const void* __restrict__ Ap,
    const float* __restrict__ Pm, const int* __restrict__ span,
    const float* __restrict__ rel, const int* __restrict__ lst,
    const int* __restrict__ offarr, const int* __restrict__ srcv,
    const u16* __restrict__ s2tab, int dst0, int dpc,
    const float* __restrict__ B, int ldb, const float* __restrict__ bias,
    void* __restrict__ Cp, int Cstride, int coff, int M) {
  constexpr int LDA = 136;  // 128 + 8 pad
  __shared__ u16 As[64 * LDA];
  __shared__ u16 Bs[64 * LDA];
  int e_start = 0, eM = M;
  if (AMODE == 2) {
    e_start = dst0 ? offarr[dst0 - 1] : 0;
    int e_end = offarr[dst0 + dpc - 1];
    int len = e_end - e_start;
    eM = len < M ? len : M;  // M = buffer capacity
  }
  const int m0 = blockIdx.x * 64, n0 = blockIdx.y * 64;
  if (m0 >= eM) return;
  const int t = threadIdx.x;
  const int wave = t >> 6, lane = t & 63, lrow = lane & 15, quad = lane >> 4;

  f32x4 acc[4] = {{0.f, 0.f, 0.f, 0.f}, {0.f, 0.f, 0.f, 0.f},
                  {0.f, 0.f, 0.f, 0.f}, {0.f, 0.f, 0.f, 0.f}};

  for (int k2 = 0; k2 < 2; k2++) {
    const int kbase = k2 * 128;
    if (k2) __syncthreads();
#pragma unroll
    for (int i = 0; i < 4; i++) {
      int c = t + i * 256;  // 1024 chunks of 8 elems = 64 rows x 128 cols
      int row = c >> 4, col = (c & 15) * 8;
      int gm = m0 + row;
      uint4 va; va.x = va.y = va.z = va.w = 0u;
      if (AMODE == 0) {
        if (gm < eM) {
          if (ASRC == 0) {
            const float* af = (const float*)Ap + (size_t)gm * 256 + kbase + col;
            va = pack8(*(const float4*)af, *(const float4*)(af + 4));
          } else {
            va = *(const uint4*)((const u16*)Ap + (size_t)gm * 256 + kbase + col);
          }
        }
      } else {
        if (gm < eM) {
          int e = lst[e_start + gm];
          int xx = span[2 * e], yy = span[2 * e + 1];
          float sc = rel[e] / (float)(yy - xx);
          const float* py = Pm + (size_t)yy * 256 + kbase + col;
          const float* px = Pm + (size_t)xx * 256 + kbase + col;
          float4 ya = *(const float4*)py, yb = *(const float4*)(py + 4);
          float4 xa = *(const float4*)px, xb = *(const float4*)(px + 4);
          float4 d0 = {(ya.x - xa.x) * sc, (ya.y - xa.y) * sc,
                       (ya.z - xa.z) * sc, (ya.w - xa.w) * sc};
          float4 d1 = {(yb.x - xb.x) * sc, (yb.y - xb.y) * sc,
                       (yb.z - xb.z) * sc, (yb.w - xb.w) * sc};
          va = pack8(d0, d1);
        }
      }
      *(uint4*)&As[row * LDA + col] = va;
      const float* bf = B + (size_t)(n0 + row) * ldb + kbase + col;
      uint4 vb = pack8(*(const float4*)bf, *(const float4*)(bf + 4));
      *(uint4*)&Bs[row * LDA + col] = vb;
    }
    __syncthreads();
    const u16* ab = &As[(wave * 16 + lrow) * LDA + quad * 8];
    const u16* bb = &Bs[lrow * LDA + quad * 8];
#pragma unroll
    for (int kk = 0; kk < 128; kk += 32) {
      bf16x8 av = *(const bf16x8*)(ab + kk);
#pragma unroll
      for (int j = 0; j < 4; j++) {
        bf16x8 bv = *(const bf16x8*)(bb + j * 16 * LDA + kk);
        acc[j] = __builtin_amdgcn_mfma_f32_16x16x32_bf16(av, bv, acc[j], 0, 0, 0);
      }
    }
  }
  // C/D layout: col = lane&15, row = quad*4 + reg  [guide m89-verified]
#pragma unroll
  for (int j = 0; j < 4; j++) {
    int n = n0 + j * 16 + lrow;
    float bv = bias ? bias[n] : 0.f;
#pragma unroll
    for (int r = 0; r < 4; r++) {
      int m = m0 + wave * 16 + quad * 4 + r;
      if (m < eM) {
        float v = acc[j][r] + bv;
        if (AMODE == 2) {
          int e = lst[e_start + m];
          v += us2f(s2tab[(size_t)srcv[e] * 512 + n]);
        }
        if (OUTBF) ((u16*)Cp)[(size_t)m * Cstride + coff + n] = f2us(v);
        else       ((float*)Cp)[(size_t)m * Cstride + coff + n] = v;
      }
    }
  }
}

// ---------------- segment softmax aggregations -----------------------------
__global__ __launch_bounds__(256) void agg_ts(
    const int* __restrict__ off, const int* __restrict__ list,
    const int* __restrict__ src, const u16* __restrict__ a_src,
    const u16* __restrict__ a_dst, const u16* __restrict__ u_tok,
    float* __restrict__ out) {
  int i = blockIdx.x, d = threadIdx.x;
  int s0 = i ? off[i - 1] : 0, s1 = off[i];
  float ad = us2f(a_dst[(size_t)i * 256 + d]);
  float num = 0.f, den = 0.f;
  for (int p = s0; p < s1; p++) {
    int s = src[list[p]];
    float v = us2f(a_src[(size_t)s * 256 + d]) + ad;
    v = v >= 0.f ? v : 0.01f * v;
    float ex = __expf(v);
    den += ex;
    num += ex * us2f(u_tok[(size_t)s * 256 + d]);
  }
  out[(size_t)i * 256 + d] = num / fmaxf(den, 1e-9f);
}

// EE: buf rows are chunk-local [m_ee(256) | attpre(256)] bf16
__global__ __launch_bounds__(256) void agg_ee_chunk(
    const int* __restrict__ off, const u16* __restrict__ buf,
    const u16* __restrict__ adp, float* __restrict__ out, int dst0) {
  int i = dst0 + blockIdx.x, d = threadIdx.x;
  int e_start = dst0 ? off[dst0 - 1] : 0;
  int s0 = i ? off[i - 1] : 0, s1 = off[i];
  float ad = us2f(adp[(size_t)i * 256 + d]);
  float num = 0.f, den = 0.f;
  for (int p = s0; p < s1; p++) {
    size_t row = (size_t)(p - e_start) * 512;
    float v = us2f(buf[row + 256 + d]) + ad;
    v = v >= 0.f ? v : 0.01f * v;
    float ex = __expf(v);
    den += ex;
    num += ex * us2f(buf[row + d]);
  }
  out[(size_t)i * 256 + d] = num / fmaxf(den, 1e-9f);
}

// GRU per edge + segment sum; gi bf16 global by src, gh bf16 chunk-local,
// h = feat_tok (f32), out bf16.
__global__ __launch_bounds__(256) void agg_gru(
    const int* __restrict__ off, const int* __restrict__ list,
    const int* __restrict__ src, const u16* __restrict__ gi,
    const u16* __restrict__ ghc, const float* __restrict__ feat,
    u16* __restrict__ out, int tok0) {
  int i = tok0 + blockIdx.x, d = threadIdx.x;
  int s0 = i ? off[i - 1] : 0, s1 = off[i];
  size_t b = (size_t)blockIdx.x * 768;
  float ghr = us2f(ghc[b + d]), ghz = us2f(ghc[b + 256 + d]), ghn = us2f(ghc[b + 512 + d]);
  float h = feat[(size_t)i * 256 + d];
  float sum = 0.f;
  for (int p = s0; p < s1; p++) {
    int s = src[list[p]];
    size_t g = (size_t)s * 768;
    float r = sigm(us2f(gi[g + d]) + ghr);
    float z = sigm(us2f(gi[g + 256 + d]) + ghz);
    float n = tanh_f(us2f(gi[g + 512 + d]) + r * ghn);
    sum += (1.f - z) * n + z * h;
  }
  out[(size_t)i * 256 + d] = f2us(sum);
}

// node GRU combine; gi/gh chunk-local f32, hprev bf16 global, out bf16 or f32.
template <bool OUTBF>
__global__ __launch_bounds__(256) void gru_combine(
    const float* __restrict__ gi, const float* __restrict__ gh,
    const u16* __restrict__ hprev, void* __restrict__ out, int row0) {
  int i = blockIdx.x, d = threadIdx.x;
  size_t g = (size_t)i * 768;
  float h = us2f(hprev[(size_t)(row0 + i) * 256 + d]);
  float r = sigm(gi[g + d] + gh[g + d]);
  float z = sigm(gi[g + 256 + d] + gh[g + 256 + d]);
  float n = tanh_f(gi[g + 512 + d] + r * gh[g + 512 + d]);
  float v = (1.f - z) * n + z * h;
  if (OUTBF) ((u16*)out)[(size_t)(row0 + i) * 256 + d] = f2us(v);
  else       ((float*)out)[(size_t)(row0 + i) * 256 + d] = v;
}

// ---------------------------------------------------------------------------
extern "C" void kernel_launch(void* const* d_in, const int* in_sizes, int n_in,
                              void* d_out, int out_size, void* d_ws, size_t ws_size,
                              hipStream_t stream) {
  const float* feat_tok = (const float*)d_in[0];
  const float* feat_srl = (const float*)d_in[1];
  const float* feat_ent = (const float*)d_in[2];
  const float* bert     = (const float*)d_in[3];
  const float* rel_type = (const float*)d_in[4];
  const int* src_ts = (const int*)d_in[5];
  const int* dst_ts = (const int*)d_in[6];
  const int* src_ee = (const int*)d_in[7];
  const int* dst_ee = (const int*)d_in[8];
  const int* src_st = (const int*)d_in[9];
  const int* dst_st = (const int*)d_in[10];
  const int* src_et = (const int*)d_in[11];
  const int* dst_et = (const int*)d_in[12];
  const int* span   = (const int*)d_in[13];
  const float* Wn   = (const float*)d_in[14];
  const float* bn   = (const float*)d_in[15];
  const float* Watt = (const float*)d_in[16];  // 256 x 512 : [A1 | A2]
  const float* batt = (const float*)d_in[17];
  const float* Wrel = (const float*)d_in[18];  // 256 x 512 : [Wr1 | Wr2]
  const float* brel = (const float*)d_in[19];
  const float* Wc   = (const float*)d_in[20];
  const float* bc   = (const float*)d_in[21];
  const float* Wih  = (const float*)d_in[22];  // 768 x 256
  const float* Whh  = (const float*)d_in[23];
  const float* bih  = (const float*)d_in[24];
  const float* bhh  = (const float*)d_in[25];

  // ---- workspace overlays (phase lifetimes in comments) -------------------
  char* W = (char*)d_ws;
  float* Pm    = (float*)(W + 0);                  // P1/P2: 51,201,024
  u16* u_tok   = (u16*)(W + 51250240);             // P1: 25.6M
  u16* a_src   = (u16*)(W + 76850240);             // P1: 25.6M
  u16* p_srl   = (u16*)(W + 102450240);            // P1: 10.24M
  u16* a_dst   = (u16*)(W + 112690240);            // P1: 10.24M
  u16* s_ent   = (u16*)(W + 51250240);             // P2 (TS dead): 5.12M
  u16* p_ent   = (u16*)(W + 56370240);             // P2: 5.12M
  u16* meeatt  = (u16*)(W + 51250240);             // P2 chunks: 76.8M
  float* WW    = (float*)(W + 138000000);          // P2: 524,288
  float* B2    = (float*)(W + 138600000);          // P2: 262,144
  float* bias2 = (float*)(W + 138900000);          // P2: 1,024
  u16* s2tab   = (u16*)(W + 139000000);            // P2: 10.24M
  u16* adp     = (u16*)(W + 149300032);            // P2: 5.12M
  u16* gi_srl  = (u16*)(W + 0);                    // P3 (Pm dead): 30.72M
  u16* gi_ent  = (u16*)(W + 30720000);             // P3: 15.36M
  u16* ghc     = (u16*)(W + 51250240);             // P3: 38.4M
  u16* hst     = (u16*)(W + 115300096);            // P3->P4: 25.6M
  u16* het     = (u16*)(W + 140900096);            // P3->P4 (P2 tables dead): 25.6M
  float* giA   = (float*)(W + 0);                  // P4/P5: 38.4M
  float* ghA   = (float*)(W + 38400000);           // P4/P5: 38.4M
  u16* h1      = (u16*)(W + 76800000);             // P4->P5: 25.6M
  int* ts_off = (int*)(W + 166500096);
  int* ts_lst = (int*)(W + 166580096);
  int* ee_off = (int*)(W + 167780096);
  int* ee_lst = (int*)(W + 167820096);
  int* st_off = (int*)(W + 168420096);
  int* st_lst = (int*)(W + 168620096);
  int* et_off = (int*)(W + 169820096);
  int* et_lst = (int*)(W + 170020096);
  constexpr size_t NEED = 170620096;

  float* out_htok = (float*)d_out;
  float* out_hsrl = (float*)d_out + 12800000;
  float* out_hent = (float*)d_out + 17920000;

  if (ws_size < NEED) {  // sentinel: absmax ~= 1000 + ws_MB decodes ws_size
    fill_sent<<<(out_size + 255) / 256, 256, 0, stream>>>(
        (float*)d_out, out_size, 1000.f + (float)(ws_size >> 20));
    return;
  }

  // ---- CSR builds ---------------------------------------------------------
  hipMemsetAsync(ts_off, 0, 20000 * 4, stream);
  hipMemsetAsync(ee_off, 0, 10000 * 4, stream);
  hipMemsetAsync(st_off, 0, 50000 * 4, stream);
  hipMemsetAsync(et_off, 0, 50000 * 4, stream);
  count_k<<<1172, 256, 0, stream>>>(dst_ts, 300000, ts_off);
  count_k<<<586, 256, 0, stream>>>(dst_ee, 150000, ee_off);
  count_k<<<1172, 256, 0, stream>>>(dst_st, 300000, st_off);
  count_k<<<586, 256, 0, stream>>>(dst_et, 150000, et_off);
  scan4_k<<<4, 1024, 0, stream>>>(ts_off, 20000, ee_off, 10000, st_off, 50000, et_off, 50000);
  fill_k<<<1172, 256, 0, stream>>>(dst_ts, 300000, ts_off, ts_lst);
  fill_k<<<586, 256, 0, stream>>>(dst_ee, 150000, ee_off, ee_lst);
  fill_k<<<1172, 256, 0, stream>>>(dst_st, 300000, st_off, st_lst);
  fill_k<<<586, 256, 0, stream>>>(dst_et, 150000, et_off, et_lst);

  cumsum_P<<<256, 256, 0, stream>>>(bert, Pm);
  make_B2<<<256, 256, 0, stream>>>(Watt, Wc, B2);
  make_bias2<<<1, 256, 0, stream>>>(Watt, bc, bias2);
  make_WW<<<512, 256, 0, stream>>>(Wc, B2, Wrel, WW);

  // ---- P1: TS attention -> h_srl (f32 out) --------------------------------
  gemm_k256<0, 0, true><<<dim3(782, 4), 256, 0, stream>>>(
      feat_tok, nullptr, nullptr, nullptr, nullptr, nullptr, nullptr, nullptr, 0, 0,
      Wn, 256, bn, u_tok, 256, 0, 50000);
  gemm_k256<0, 1, true><<<dim3(782, 4), 256, 0, stream>>>(
      u_tok, nullptr, nullptr, nullptr, nullptr, nullptr, nullptr, nullptr, 0, 0,
      Watt, 512, nullptr, a_src, 256, 0, 50000);
  gemm_k256<0, 0, true><<<dim3(313, 4), 256, 0, stream>>>(
      feat_srl, nullptr, nullptr, nullptr, nullptr, nullptr, nullptr, nullptr, 0, 0,
      Wn, 256, bn, p_srl, 256, 0, 20000);
  gemm_k256<0, 1, true><<<dim3(313, 4), 256, 0, stream>>>(
      p_srl, nullptr, nullptr, nullptr, nullptr, nullptr, nullptr, nullptr, 0, 0,
      Watt + 256, 512, batt, a_dst, 256, 0, 20000);
  agg_ts<<<20000, 256, 0, stream>>>(ts_off, ts_lst, src_ts, a_src, a_dst, u_tok, out_hsrl);

  // ---- P2: EE attention -> h_ent ------------------------------------------
  gemm_k256<0, 0, true><<<dim3(157, 4), 256, 0, stream>>>(
      feat_ent, nullptr, nullptr, nullptr, nullptr, nullptr, nullptr, nullptr, 0, 0,
      Wrel, 512, brel, s_ent, 256, 0, 10000);
  gemm_k256<0, 0, true><<<dim3(157, 4), 256, 0, stream>>>(
      feat_ent, nullptr, nullptr, nullptr, nullptr, nullptr, nullptr, nullptr, 0, 0,
      Wn, 256, bn, p_ent, 256, 0, 10000);
  gemm_k256<0, 1, true><<<dim3(157, 4), 256, 0, stream>>>(
      s_ent, nullptr, nullptr, nullptr, nullptr, nullptr, nullptr, nullptr, 0, 0,
      Wc, 256, bc, s2tab, 512, 0, 10000);
  gemm_k256<0, 1, true><<<dim3(157, 4), 256, 0, stream>>>(
      s_ent, nullptr, nullptr, nullptr, nullptr, nullptr, nullptr, nullptr, 0, 0,
      B2, 256, bias2, s2tab, 512, 256, 10000);
  gemm_k256<0, 1, true><<<dim3(157, 4), 256, 0, stream>>>(
      p_ent, nullptr, nullptr, nullptr, nullptr, nullptr, nullptr, nullptr, 0, 0,
      Watt + 256, 512, batt, adp, 256, 0, 10000);
  for (int c = 0; c < 4; c++) {  // 4 x 2500 dsts (37500 edges, cap 75000)
    gemm_k256<2, 0, true><<<dim3(1172, 8), 256, 0, stream>>>(
        nullptr, Pm, span, rel_type, ee_lst, ee_off, src_ee, s2tab, c * 2500, 2500,
        WW, 256, nullptr, meeatt, 512, 0, 75000);
    agg_ee_chunk<<<2500, 256, 0, stream>>>(ee_off, meeatt, adp, out_hent, c * 2500);
  }

  // ---- P3: GRU gate tables + edge GRU aggregations ------------------------
  gemm_k256<0, 0, true><<<dim3(313, 12), 256, 0, stream>>>(
      out_hsrl, nullptr, nullptr, nullptr, nullptr, nullptr, nullptr, nullptr, 0, 0,
      Wih, 256, bih, gi_srl, 768, 0, 20000);
  gemm_k256<0, 0, true><<<dim3(157, 12), 256, 0, stream>>>(
      out_hent, nullptr, nullptr, nullptr, nullptr, nullptr, nullptr, nullptr, 0, 0,
      Wih, 256, bih, gi_ent, 768, 0, 10000);
  for (int c = 0; c < 2; c++) {  // gh chunks of 25000 tokens
    int base = c * 25000;
    gemm_k256<0, 0, true><<<dim3(391, 12), 256, 0, stream>>>(
        feat_tok + (size_t)base * 256, nullptr, nullptr, nullptr, nullptr, nullptr,
        nullptr, nullptr, 0, 0, Whh, 256, bhh, ghc, 768, 0, 25000);
    agg_gru<<<25000, 256, 0, stream>>>(st_off, st_lst, src_st, gi_srl, ghc, feat_tok, hst, base);
    agg_gru<<<25000, 256, 0, stream>>>(et_off, et_lst, src_et, gi_ent, ghc, feat_tok, het, base);
  }

  // ---- P4: h1 = GRU(x=h_ent_tok, h=h_srl_tok), 4 x 12500 rows -------------
  for (int c = 0; c < 4; c++) {
    int base = c * 12500;
    gemm_k256<0, 1, false><<<dim3(196, 12), 256, 0, stream>>>(
        het + (size_t)base * 256, nullptr, nullptr, nullptr, nullptr, nullptr,
        nullptr, nullptr, 0, 0, Wih, 256, bih, giA, 768, 0, 12500);
    gemm_k256<0, 1, false><<<dim3(196, 12), 256, 0, stream>>>(
        hst + (size_t)base * 256, nullptr, nullptr, nullptr, nullptr, nullptr,
        nullptr, nullptr, 0, 0, Whh, 256, bhh, ghA, 768, 0, 12500);
    gru_combine<true><<<12500, 256, 0, stream>>>(giA, ghA, hst, h1, base);
  }
  // ---- P5: h_tok = GRU(x=feat_tok, h=h1) (f32 out) ------------------------
  for (int c = 0; c < 4; c++) {
    int base = c * 12500;
    gemm_k256<0, 0, false><<<dim3(196, 12), 256, 0, stream>>>(
        feat_tok + (size_t)base * 256, nullptr, nullptr, nullptr, nullptr, nullptr,
        nullptr, nullptr, 0, 0, Wih, 256, bih, giA, 768, 0, 12500);
    gemm_k256<0, 1, false><<<dim3(196, 12), 256, 0, stream>>>(
        h1 + (size_t)base * 256, nullptr, nullptr, nullptr, nullptr, nullptr,
        nullptr, nullptr, 0, 0, Whh, 256, bhh, ghA, 768, 0, 12500);
    gru_combine<false><<<12500, 256, 0, stream>>>(giA, ghA, h1, out_htok, base);
  }
}

// Round 4
// 2298.650 us; speedup vs baseline: 1.1445x; 1.1445x over previous
//
#include <hip/hip_runtime.h>
#include <stdint.h>

// ---------------------------------------------------------------------------
// HeteroRGCNLayer on MI355X. Inputs/outputs float32; MFMA compute in bf16.
// D=256, N_TOK=50000, N_SRL=20000, N_ENT=10000, T=50000
// E_TS=300000, E_EE=150000, E_ST=300000, E_ET=150000
// R4: coalesced 3-pass cumsum; GEMM stages A once per block and loops n-tiles
// (A HBM refetch 12x -> <=3x); EE edge GEMM grid right-sized (covering dst =>
// exactly 15 edges/ent, 37500 per 2500-dst chunk).
// ---------------------------------------------------------------------------

typedef unsigned short u16;
typedef __bf16 bf16_t;
typedef bf16_t bf16x8 __attribute__((ext_vector_type(8)));
typedef float f32x4 __attribute__((ext_vector_type(4)));

__device__ __forceinline__ float us2f(u16 h) {
  unsigned int u = ((unsigned int)h) << 16;
  return __builtin_bit_cast(float, u);
}
__device__ __forceinline__ u16 f2us(float f) {  // RNE float->bf16
  unsigned int u = __builtin_bit_cast(unsigned int, f);
  u += 0x7FFFu + ((u >> 16) & 1u);
  return (u16)(u >> 16);
}
__device__ __forceinline__ uint4 pack8(float4 a, float4 b) {
  uint4 v;
  v.x = f2us(a.x) | ((unsigned)f2us(a.y) << 16);
  v.y = f2us(a.z) | ((unsigned)f2us(a.w) << 16);
  v.z = f2us(b.x) | ((unsigned)f2us(b.y) << 16);
  v.w = f2us(b.z) | ((unsigned)f2us(b.w) << 16);
  return v;
}
__device__ __forceinline__ float sigm(float x) { return 1.f / (1.f + __expf(-x)); }
__device__ __forceinline__ float tanh_f(float x) {
  x = fminf(fmaxf(x, -15.f), 15.f);
  float e = __expf(2.f * x);
  return (e - 1.f) / (e + 1.f);
}

// ---------------- diagnostics ---------------------------------------------
__global__ void fill_sent(float* out, int n, float v) {
  int i = blockIdx.x * 256 + threadIdx.x;
  if (i < n) out[i] = v;
}

// ---------------- CSR build ------------------------------------------------
__global__ void count_k(const int* __restrict__ dst, int E, int* __restrict__ cnt) {
  int i = blockIdx.x * 256 + threadIdx.x;
  if (i < E) atomicAdd(&cnt[dst[i]], 1);
}

__global__ __launch_bounds__(1024) void scan4_k(int* a0, int n0, int* a1, int n1,
                                                int* a2, int n2, int* a3, int n3) {
  int* a; int n;
  if (blockIdx.x == 0) { a = a0; n = n0; }
  else if (blockIdx.x == 1) { a = a1; n = n1; }
  else if (blockIdx.x == 2) { a = a2; n = n2; }
  else { a = a3; n = n3; }
  __shared__ int swv[16];
  const int t = threadIdx.x, lane = t & 63, wid = t >> 6;
  int carry = 0;
  for (int base = 0; base < n; base += 1024) {
    int r = base + t;
    int v = (r < n) ? a[r] : 0;
    int inc = v;
#pragma unroll
    for (int o = 1; o < 64; o <<= 1) {
      int x = __shfl_up(inc, o, 64);
      if (lane >= o) inc += x;
    }
    if (lane == 63) swv[wid] = inc;
    __syncthreads();
    int wbase = 0, tot = 0;
    for (int w = 0; w < 16; w++) { int s = swv[w]; tot += s; if (w < wid) wbase += s; }
    if (r < n) a[r] = carry + wbase + inc - v;  // exclusive prefix
    carry += tot;
    __syncthreads();
  }
}

__global__ void fill_k(const int* __restrict__ dst, int E, int* __restrict__ off,
                       int* __restrict__ list) {
  int i = blockIdx.x * 256 + threadIdx.x;
  if (i < E) {
    int p = atomicAdd(&off[dst[i]], 1);
    list[p] = i;
  }
}

// ---------------- coalesced 3-pass prefix sum of bert emb ------------------
// chunk = 64 rows per block, 782 blocks; thread t owns dim t (coalesced rows).
__global__ __launch_bounds__(256) void cumsum_p1(const float* __restrict__ emb,
                                                 float* __restrict__ bsum) {
  int b = blockIdx.x, t = threadIdx.x;
  int r0 = b * 64, r1 = min(r0 + 64, 50000);
  float acc = 0.f;
  for (int r = r0; r < r1; r++) acc += emb[(size_t)r * 256 + t];
  bsum[(size_t)b * 256 + t] = acc;
}
__global__ __launch_bounds__(256) void cumsum_p2(float* __restrict__ bsum, int nb) {
  int t = threadIdx.x;
  float acc = 0.f;
  for (int b = 0; b < nb; b++) {
    float v = bsum[(size_t)b * 256 + t];
    bsum[(size_t)b * 256 + t] = acc;  // exclusive block prefix
    acc += v;
  }
}
__global__ __launch_bounds__(256) void cumsum_p3(const float* __restrict__ emb,
                                                 const float* __restrict__ bsum,
                                                 float* __restrict__ Pm) {
  int b = blockIdx.x, t = threadIdx.x;
  int r0 = b * 64, r1 = min(r0 + 64, 50000);
  float acc = bsum[(size_t)b * 256 + t];
  if (b == 0) Pm[t] = 0.f;
  for (int r = r0; r < r1; r++) {
    acc += emb[(size_t)r * 256 + t];
    Pm[(size_t)(r + 1) * 256 + t] = acc;
  }
}

// ---------------- derived weights (f32) ------------------------------------
__global__ __launch_bounds__(256) void make_B2(const float* __restrict__ Watt,
                                               const float* __restrict__ Wc,
                                               float* __restrict__ B2) {
  int r = blockIdx.x, k = threadIdx.x;
  float s = 0.f;
  for (int n = 0; n < 256; n++) s += Watt[r * 512 + n] * Wc[n * 256 + k];
  B2[r * 256 + k] = s;
}
__global__ void make_bias2(const float* __restrict__ Watt, const float* __restrict__ bc,
                           float* __restrict__ bias2) {
  int r = threadIdx.x;
  float s = 0.f;
  for (int k = 0; k < 256; k++) s += Watt[r * 512 + k] * bc[k];
  bias2[r] = s;
}
// WW (512x256): rows 0..255 = Wc@Wr2 ; rows 256..511 = B2@Wr2
__global__ __launch_bounds__(256) void make_WW(const float* __restrict__ Wc,
                                               const float* __restrict__ B2,
                                               const float* __restrict__ Wrel,
                                               float* __restrict__ WW) {
  int r = blockIdx.x, k = threadIdx.x;
  const float* X = (r < 256) ? (Wc + (size_t)r * 256) : (B2 + (size_t)(r - 256) * 256);
  float s = 0.f;
  for (int n = 0; n < 256; n++) s += X[n] * Wrel[(size_t)n * 512 + 256 + k];
  WW[(size_t)r * 256 + k] = s;
}

// ---------------------------------------------------------------------------
// N-loop GEMM: C[M x *] = A[M x 256] @ B^T + bias.
// A staged ONCE in LDS (full K, 64 rows), then NT n-tiles of 64 cols looped
// inside the block (B half-K tiles). grid.y selects the NT-tile group.
// AMODE 0: A from memory (ASRC 0 = f32, 1 = bf16). AMODE 2: EE edges — row m
// is edge lst[e_start+m], A[k] = rel/(y-x)*(Pm[y][k]-Pm[x][k]); s2tab residual.
// LDS: As 64x264x2B=33.8K + Bs 64x136x2B=17.4K = 51.2 KB -> 3 blocks/CU.
// ---------------------------------------------------------------------------
template <int AMODE, int ASRC, bool OUTBF>
__global__ __launch_bounds__(256) void gemm_nl(
    const void* __restrict__ Ap,
    const float* __restrict__ Pm, const int* __restrict__ span,
    const float* __restrict__ rel, const int* __restrict__ lst,
    const int* __restrict__ offarr, const int* __restrict__ srcv,
    const u16* __restrict__ s2tab, int dst0, int dpc,
    const float* __restrict__ B, int ldb, const float* __restrict__ bias,
    void* __restrict__ Cp, int Cstride, int coff, int M, int NT) {
  constexpr int LDA = 264, LDB = 136;
  __shared__ u16 As[64 * LDA];
  __shared__ u16 Bs[64 * LDB];
  int e_start = 0, eM = M;
  if (AMODE == 2) {
    e_start = dst0 ? offarr[dst0 - 1] : 0;
    int len = offarr[dst0 + dpc - 1] - e_start;
    eM = len < M ? len : M;
  }
  const int m0 = blockIdx.x * 64;
  if (m0 >= eM) return;
  const int nbase = blockIdx.y * NT * 64;
  const int t = threadIdx.x;
  const int wave = t >> 6, lane = t & 63, lrow = lane & 15, quad = lane >> 4;

  // ---- stage As full-K (2048 8-elem chunks / 256 threads = 8 iters) ----
#pragma unroll
  for (int i = 0; i < 8; i++) {
    int c = t + i * 256;
    int row = c >> 5, col = (c & 31) * 8;
    int gm = m0 + row;
    uint4 va; va.x = va.y = va.z = va.w = 0u;
    if (gm < eM) {
      if (AMODE == 0) {
        if (ASRC == 0) {
          const float* af = (const float*)Ap + (size_t)gm * 256 + col;
          va = pack8(*(const float4*)af, *(const float4*)(af + 4));
        } else {
          va = *(const uint4*)((const u16*)Ap + (size_t)gm * 256 + col);
        }
      } else {
        int e = lst[e_start + gm];
        int xx = span[2 * e], yy = span[2 * e + 1];
        float sc = rel[e] / (float)(yy - xx);
        const float* py = Pm + (size_t)yy * 256 + col;
        const float* px = Pm + (size_t)xx * 256 + col;
        float4 ya = *(const float4*)py, yb = *(const float4*)(py + 4);
        float4 xa = *(const float4*)px, xb = *(const float4*)(px + 4);
        float4 d0 = {(ya.x - xa.x) * sc, (ya.y - xa.y) * sc,
                     (ya.z - xa.z) * sc, (ya.w - xa.w) * sc};
        float4 d1 = {(yb.x - xb.x) * sc, (yb.y - xb.y) * sc,
                     (yb.z - xb.z) * sc, (yb.w - xb.w) * sc};
        va = pack8(d0, d1);
      }
    }
    *(uint4*)&As[row * LDA + col] = va;
  }

  for (int nt = 0; nt < NT; nt++) {
    const int n0 = nbase + nt * 64;
    f32x4 acc[4] = {{0.f, 0.f, 0.f, 0.f}, {0.f, 0.f, 0.f, 0.f},
                    {0.f, 0.f, 0.f, 0.f}, {0.f, 0.f, 0.f, 0.f}};
    for (int k2 = 0; k2 < 2; k2++) {
      __syncthreads();  // As visible (nt=0); prior Bs reads done
#pragma unroll
      for (int i = 0; i < 4; i++) {
        int c = t + i * 256;
        int row = c >> 4, col = (c & 15) * 8;
        const float* bf = B + (size_t)(n0 + row) * ldb + k2 * 128 + col;
        uint4 vb = pack8(*(const float4*)bf, *(const float4*)(bf + 4));
        *(uint4*)&Bs[row * LDB + col] = vb;
      }
      __syncthreads();
      const u16* ab = &As[(wave * 16 + lrow) * LDA + k2 * 128 + quad * 8];
      const u16* bb = &Bs[lrow * LDB + quad * 8];
#pragma unroll
      for (int kk = 0; kk < 128; kk += 32) {
        bf16x8 av = *(const bf16x8*)(ab + kk);
#pragma unroll
        for (int j = 0; j < 4; j++) {
          bf16x8 bv = *(const bf16x8*)(bb + j * 16 * LDB + kk);
          acc[j] = __builtin_amdgcn_mfma_f32_16x16x32_bf16(av, bv, acc[j], 0, 0, 0);
        }
      }
    }
    // epilogue: C/D layout col = lane&15, row = quad*4 + reg
#pragma unroll
    for (int r = 0; r < 4; r++) {
      int m = m0 + wave * 16 + quad * 4 + r;
      if (m < eM) {
        float resv = 0.f;
        const u16* srow = nullptr;
        if (AMODE == 2) {
          int e = lst[e_start + m];
          srow = s2tab + (size_t)srcv[e] * 512;
        }
#pragma unroll
        for (int j = 0; j < 4; j++) {
          int n = n0 + j * 16 + lrow;
          float v = acc[j][r] + (bias ? bias[n] : 0.f);
          if (AMODE == 2) v += us2f(srow[n]);
          (void)resv;
          if (OUTBF) ((u16*)Cp)[(size_t)m * Cstride + coff + n] = f2us(v);
          else       ((float*)Cp)[(size_t)m * Cstride + coff + n] = v;
        }
      }
    }
  }
}

// ---------------- segment softmax aggregations -----------------------------
__global__ __launch_bounds__(256) void agg_ts(
    const int* __restrict__ off, const int* __restrict__ list,
    const int* __restrict__ src, const u16* __restrict__ a_src,
    const u16* __restrict__ a_dst, const u16* __restrict__ u_tok,
    float* __restrict__ out) {
  int i = blockIdx.x, d = threadIdx.x;
  int s0 = i ? off[i - 1] : 0, s1 = off[i];
  float ad = us2f(a_dst[(size_t)i * 256 + d]);
  float num = 0.f, den = 0.f;
  for (int p = s0; p < s1; p++) {
    int s = src[list[p]];
    float v = us2f(a_src[(size_t)s * 256 + d]) + ad;
    v = v >= 0.f ? v : 0.01f * v;
    float ex = __expf(v);
    den += ex;
    num += ex * us2f(u_tok[(size_t)s * 256 + d]);
  }
  out[(size_t)i * 256 + d] = num / fmaxf(den, 1e-9f);
}

// EE: buf rows chunk-local [m_ee(256) | attpre(256)] bf16
__global__ __launch_bounds__(256) void agg_ee_chunk(
    const int* __restrict__ off, const u16* __restrict__ buf,
    const u16* __restrict__ adp, float* __restrict__ out, int dst0) {
  int i = dst0 + blockIdx.x, d = threadIdx.x;
  int e_start = dst0 ? off[dst0 - 1] : 0;
  int s0 = i ? off[i - 1] : 0, s1 = off[i];
  float ad = us2f(adp[(size_t)i * 256 + d]);
  float num = 0.f, den = 0.f;
  for (int p = s0; p < s1; p++) {
    size_t row = (size_t)(p - e_start) * 512;
    float v = us2f(buf[row + 256 + d]) + ad;
    v = v >= 0.f ? v : 0.01f * v;
    float ex = __expf(v);
    den += ex;
    num += ex * us2f(buf[row + d]);
  }
  out[(size_t)i * 256 + d] = num / fmaxf(den, 1e-9f);
}

// GRU per edge + segment sum; gi bf16 by src, gh bf16 chunk-local by dst.
__global__ __launch_bounds__(256) void agg_gru(
    const int* __restrict__ off, const int* __restrict__ list,
    const int* __restrict__ src, const u16* __restrict__ gi,
    const u16* __restrict__ ghc, const float* __restrict__ feat,
    u16* __restrict__ out, int tok0) {
  int i = tok0 + blockIdx.x, d = threadIdx.x;
  int s0 = i ? off[i - 1] : 0, s1 = off[i];
  size_t b = (size_t)blockIdx.x * 768;
  float ghr = us2f(ghc[b + d]), ghz = us2f(ghc[b + 256 + d]), ghn = us2f(ghc[b + 512 + d]);
  float h = feat[(size_t)i * 256 + d];
  float sum = 0.f;
  for (int p = s0; p < s1; p++) {
    int s = src[list[p]];
    size_t g = (size_t)s * 768;
    float r = sigm(us2f(gi[g + d]) + ghr);
    float z = sigm(us2f(gi[g + 256 + d]) + ghz);
    float n = tanh_f(us2f(gi[g + 512 + d]) + r * ghn);
    sum += (1.f - z) * n + z * h;
  }
  out[(size_t)i * 256 + d] = f2us(sum);
}

// node GRU combine; gi/gh chunk-local f32, hprev bf16 global.
template <bool OUTBF>
__global__ __launch_bounds__(256) void gru_combine(
    const float* __restrict__ gi, const float* __restrict__ gh,
    const u16* __restrict__ hprev, void* __restrict__ out, int row0) {
  int i = blockIdx.x, d = threadIdx.x;
  size_t g = (size_t)i * 768;
  float h = us2f(hprev[(size_t)(row0 + i) * 256 + d]);
  float r = sigm(gi[g + d] + gh[g + d]);
  float z = sigm(gi[g + 256 + d] + gh[g + 256 + d]);
  float n = tanh_f(gi[g + 512 + d] + r * gh[g + 512 + d]);
  float v = (1.f - z) * n + z * h;
  if (OUTBF) ((u16*)out)[(size_t)(row0 + i) * 256 + d] = f2us(v);
  else       ((float*)out)[(size_t)(row0 + i) * 256 + d] = v;
}

// ---------------------------------------------------------------------------
extern "C" void kernel_launch(void* const* d_in, const int* in_sizes, int n_in,
                              void* d_out, int out_size, void* d_ws, size_t ws_size,
                              hipStream_t stream) {
  const float* feat_tok = (const float*)d_in[0];
  const float* feat_srl = (const float*)d_in[1];
  const float* feat_ent = (const float*)d_in[2];
  const float* bert     = (const float*)d_in[3];
  const float* rel_type = (const float*)d_in[4];
  const int* src_ts = (const int*)d_in[5];
  const int* dst_ts = (const int*)d_in[6];
  const int* src_ee = (const int*)d_in[7];
  const int* dst_ee = (const int*)d_in[8];
  const int* src_st = (const int*)d_in[9];
  const int* dst_st = (const int*)d_in[10];
  const int* src_et = (const int*)d_in[11];
  const int* dst_et = (const int*)d_in[12];
  const int* span   = (const int*)d_in[13];
  const float* Wn   = (const float*)d_in[14];
  const float* bn   = (const float*)d_in[15];
  const float* Watt = (const float*)d_in[16];  // 256 x 512 : [A1 | A2]
  const float* batt = (const float*)d_in[17];
  const float* Wrel = (const float*)d_in[18];  // 256 x 512 : [Wr1 | Wr2]
  const float* brel = (const float*)d_in[19];
  const float* Wc   = (const float*)d_in[20];
  const float* bc   = (const float*)d_in[21];
  const float* Wih  = (const float*)d_in[22];  // 768 x 256
  const float* Whh  = (const float*)d_in[23];
  const float* bih  = (const float*)d_in[24];
  const float* bhh  = (const float*)d_in[25];

  // ---- workspace overlays -------------------------------------------------
  char* W = (char*)d_ws;
  float* Pm    = (float*)(W + 0);                  // P0-P2: 51,201,024
  u16* u_tok   = (u16*)(W + 51250240);             // P1: 25.6M
  u16* a_src   = (u16*)(W + 76850240);             // P1: 25.6M
  u16* p_srl   = (u16*)(W + 102450240);            // P1: 10.24M
  u16* a_dst   = (u16*)(W + 112690240);            // P1: 10.24M
  u16* s_ent   = (u16*)(W + 51250240);             // P2 (TS dead): 5.12M
  u16* p_ent   = (u16*)(W + 56370240);             // P2: 5.12M
  u16* meeatt  = (u16*)(W + 51250240);             // P2 chunks: 40.96M used
  float* WW    = (float*)(W + 138000000);          // P2: 524,288
  float* B2    = (float*)(W + 138600000);          // P2: 262,144
  float* bias2 = (float*)(W + 138900000);          // P2: 1,024
  u16* s2tab   = (u16*)(W + 139000000);            // P2: 10.24M
  u16* adp     = (u16*)(W + 149300032);            // P2: 5.12M
  float* bsum  = (float*)(W + 155000000);          // P0: 800,768 (cumsum)
  u16* gi_srl  = (u16*)(W + 0);                    // P3 (Pm dead): 30.72M
  u16* gi_ent  = (u16*)(W + 30720000);             // P3: 15.36M
  u16* ghc     = (u16*)(W + 51250240);             // P3: 38.4M
  u16* hst     = (u16*)(W + 115300096);            // P3->P4: 25.6M
  u16* het     = (u16*)(W + 140900096);            // P3->P4: 25.6M
  float* giA   = (float*)(W + 0);                  // P4/P5: 38.4M
  float* ghA   = (float*)(W + 38400000);           // P4/P5: 38.4M
  u16* h1      = (u16*)(W + 76800000);             // P4->P5: 25.6M
  int* ts_off = (int*)(W + 166500096);
  int* ts_lst = (int*)(W + 166580096);
  int* ee_off = (int*)(W + 167780096);
  int* ee_lst = (int*)(W + 167820096);
  int* st_off = (int*)(W + 168420096);
  int* st_lst = (int*)(W + 168620096);
  int* et_off = (int*)(W + 169820096);
  int* et_lst = (int*)(W + 170020096);
  constexpr size_t NEED = 170620096;

  float* out_htok = (float*)d_out;
  float* out_hsrl = (float*)d_out + 12800000;
  float* out_hent = (float*)d_out + 17920000;

  if (ws_size < NEED) {  // sentinel: absmax ~= 1000 + ws_MB
    fill_sent<<<(out_size + 255) / 256, 256, 0, stream>>>(
        (float*)d_out, out_size, 1000.f + (float)(ws_size >> 20));
    return;
  }

  // ---- CSR builds ---------------------------------------------------------
  hipMemsetAsync(ts_off, 0, 20000 * 4, stream);
  hipMemsetAsync(ee_off, 0, 10000 * 4, stream);
  hipMemsetAsync(st_off, 0, 50000 * 4, stream);
  hipMemsetAsync(et_off, 0, 50000 * 4, stream);
  count_k<<<1172, 256, 0, stream>>>(dst_ts, 300000, ts_off);
  count_k<<<586, 256, 0, stream>>>(dst_ee, 150000, ee_off);
  count_k<<<1172, 256, 0, stream>>>(dst_st, 300000, st_off);
  count_k<<<586, 256, 0, stream>>>(dst_et, 150000, et_off);
  scan4_k<<<4, 1024, 0, stream>>>(ts_off, 20000, ee_off, 10000, st_off, 50000, et_off, 50000);
  fill_k<<<1172, 256, 0, stream>>>(dst_ts, 300000, ts_off, ts_lst);
  fill_k<<<586, 256, 0, stream>>>(dst_ee, 150000, ee_off, ee_lst);
  fill_k<<<1172, 256, 0, stream>>>(dst_st, 300000, st_off, st_lst);
  fill_k<<<586, 256, 0, stream>>>(dst_et, 150000, et_off, et_lst);

  cumsum_p1<<<782, 256, 0, stream>>>(bert, bsum);
  cumsum_p2<<<1, 256, 0, stream>>>(bsum, 782);
  cumsum_p3<<<782, 256, 0, stream>>>(bert, bsum, Pm);
  make_B2<<<256, 256, 0, stream>>>(Watt, Wc, B2);
  make_bias2<<<1, 256, 0, stream>>>(Watt, bc, bias2);
  make_WW<<<512, 256, 0, stream>>>(Wc, B2, Wrel, WW);

  // ---- P1: TS attention -> h_srl ------------------------------------------
  gemm_nl<0, 0, true><<<dim3(782, 1), 256, 0, stream>>>(
      feat_tok, nullptr, nullptr, nullptr, nullptr, nullptr, nullptr, nullptr, 0, 0,
      Wn, 256, bn, u_tok, 256, 0, 50000, 4);
  gemm_nl<0, 1, true><<<dim3(782, 1), 256, 0, stream>>>(
      u_tok, nullptr, nullptr, nullptr, nullptr, nullptr, nullptr, nullptr, 0, 0,
      Watt, 512, nullptr, a_src, 256, 0, 50000, 4);
  gemm_nl<0, 0, true><<<dim3(313, 2), 256, 0, stream>>>(
      feat_srl, nullptr, nullptr, nullptr, nullptr, nullptr, nullptr, nullptr, 0, 0,
      Wn, 256, bn, p_srl, 256, 0, 20000, 2);
  gemm_nl<0, 1, true><<<dim3(313, 2), 256, 0, stream>>>(
      p_srl, nullptr, nullptr, nullptr, nullptr, nullptr, nullptr, nullptr, 0, 0,
      Watt + 256, 512, batt, a_dst, 256, 0, 20000, 2);
  agg_ts<<<20000, 256, 0, stream>>>(ts_off, ts_lst, src_ts, a_src, a_dst, u_tok, out_hsrl);

  // ---- P2: EE attention -> h_ent ------------------------------------------
  gemm_nl<0, 0, true><<<dim3(157, 2), 256, 0, stream>>>(
      feat_ent, nullptr, nullptr, nullptr, nullptr, nullptr, nullptr, nullptr, 0, 0,
      Wrel, 512, brel, s_ent, 256, 0, 10000, 2);
  gemm_nl<0, 0, true><<<dim3(157, 2), 256, 0, stream>>>(
      feat_ent, nullptr, nullptr, nullptr, nullptr, nullptr, nullptr, nullptr, 0, 0,
      Wn, 256, bn, p_ent, 256, 0, 10000, 2);
  gemm_nl<0, 1, true><<<dim3(157, 2), 256, 0, stream>>>(
      s_ent, nullptr, nullptr, nullptr, nullptr, nullptr, nullptr, nullptr, 0, 0,
      Wc, 256, bc, s2tab, 512, 0, 10000, 2);
  gemm_nl<0, 1, true><<<dim3(157, 2), 256, 0, stream>>>(
      s_ent, nullptr, nullptr, nullptr, nullptr, nullptr, nullptr, nullptr, 0, 0,
      B2, 256, bias2, s2tab, 512, 256, 10000, 2);
  gemm_nl<0, 1, true><<<dim3(157, 2), 256, 0, stream>>>(
      p_ent, nullptr, nullptr, nullptr, nullptr, nullptr, nullptr, nullptr, 0, 0,
      Watt + 256, 512, batt, adp, 256, 0, 10000, 2);
  for (int c = 0; c < 4; c++) {  // 2500 dsts x exactly 15 edges = 37500
    gemm_nl<2, 0, true><<<dim3(625, 1), 256, 0, stream>>>(
        nullptr, Pm, span, rel_type, ee_lst, ee_off, src_ee, s2tab, c * 2500, 2500,
        WW, 256, nullptr, meeatt, 512, 0, 40000, 8);
    agg_ee_chunk<<<2500, 256, 0, stream>>>(ee_off, meeatt, adp, out_hent, c * 2500);
  }

  // ---- P3: GRU gate tables + edge GRU aggregations ------------------------
  gemm_nl<0, 0, true><<<dim3(313, 3), 256, 0, stream>>>(
      out_hsrl, nullptr, nullptr, nullptr, nullptr, nullptr, nullptr, nullptr, 0, 0,
      Wih, 256, bih, gi_srl, 768, 0, 20000, 4);
  gemm_nl<0, 0, true><<<dim3(157, 3), 256, 0, stream>>>(
      out_hent, nullptr, nullptr, nullptr, nullptr, nullptr, nullptr, nullptr, 0, 0,
      Wih, 256, bih, gi_ent, 768, 0, 10000, 4);
  for (int c = 0; c < 2; c++) {  // gh chunks of 25000 tokens
    int base = c * 25000;
    gemm_nl<0, 0, true><<<dim3(391, 3), 256, 0, stream>>>(
        feat_tok + (size_t)base * 256, nullptr, nullptr, nullptr, nullptr, nullptr,
        nullptr, nullptr, 0, 0, Whh, 256, bhh, ghc, 768, 0, 25000, 4);
    agg_gru<<<25000, 256, 0, stream>>>(st_off, st_lst, src_st, gi_srl, ghc, feat_tok, hst, base);
    agg_gru<<<25000, 256, 0, stream>>>(et_off, et_lst, src_et, gi_ent, ghc, feat_tok, het, base);
  }

  // ---- P4: h1 = GRU(x=h_ent_tok, h=h_srl_tok), 4 x 12500 rows -------------
  for (int c = 0; c < 4; c++) {
    int base = c * 12500;
    gemm_nl<0, 1, false><<<dim3(196, 3), 256, 0, stream>>>(
        het + (size_t)base * 256, nullptr, nullptr, nullptr, nullptr, nullptr,
        nullptr, nullptr, 0, 0, Wih, 256, bih, giA, 768, 0, 12500, 4);
    gemm_nl<0, 1, false><<<dim3(196, 3), 256, 0, stream>>>(
        hst + (size_t)base * 256, nullptr, nullptr, nullptr, nullptr, nullptr,
        nullptr, nullptr, 0, 0, Whh, 256, bhh, ghA, 768, 0, 12500, 4);
    gru_combine<true><<<12500, 256, 0, stream>>>(giA, ghA, hst, h1, base);
  }
  // ---- P5: h_tok = GRU(x=feat_tok, h=h1) ----------------------------------
  for (int c = 0; c < 4; c++) {
    int base = c * 12500;
    gemm_nl<0, 0, false><<<dim3(196, 3), 256, 0, stream>>>(
        feat_tok + (size_t)base * 256, nullptr, nullptr, nullptr, nullptr, nullptr,
        nullptr, nullptr, 0, 0, Wih, 256, bih, giA, 768, 0, 12500, 4);
    gemm_nl<0, 1, false><<<dim3(196, 3), 256, 0, stream>>>(
        h1 + (size_t)base * 256, nullptr, nullptr, nullptr, nullptr, nullptr,
        nullptr, nullptr, 0, 0, Whh, 256, bhh, ghA, 768, 0, 12500, 4);
    gru_combine<false><<<12500, 256, 0, stream>>>(giA, ghA, h1, out_htok, base);
  }
}